// Round 2
// baseline (1353.344 us; speedup 1.0000x reference)
//
#include <hip/hip_runtime.h>
#include <math.h>
#include <stdint.h>

// Problem constants
#define BB   32     // batch
#define HB   16     // batch per block (b-split: 2 blocks per n-group)
#define NN   2048   // input capsules
#define KK   16     // input dim
#define CC   32     // output capsules
#define DD   32     // capsule dim
#define NCOL 1024   // CC*DD
#define NPB  16     // n per block -> 128 n-groups x 2 b-halves = 256 blocks (1/CU)
#define WT   (KK * NCOL)          // 16384 floats = one 64 KB W tile
#define OSZ  (BB * NCOL)          // 32768 floats = one full o/partial image
#define NGRP (NN / NPB)           // 128 partial images
#define NSLICE 16                 // reduce tree fan-in stage 1: 128 -> 16

// async global->LDS. Global addr is per-lane; LDS dest must be the
// WAVE-UNIFORM base — HW writes lane i's 16 B at base + 16*i.
__device__ __forceinline__ void dma16(const float* g, const float* l) {
    __builtin_amdgcn_global_load_lds(
        (const __attribute__((address_space(1))) void*)(uintptr_t)g,
        (__attribute__((address_space(3))) void*)(uintptr_t)l,
        16, 0, 0);
}

// R3/R4: compiler pins 1024-thr blocks at 64 VGPR -> design for 64.
// R5 post-mortem: double-buffer version spilled (~70 MB/stage scratch writes,
// WRITE_SIZE 86 MB) because the per-iter dma lambda recomputed W + n*WT with
// opart live, AND __syncthreads' implicit vmcnt(0) at barrier B drained the
// prefetch in the same iteration it was issued -> no overlap gained.
// R6 fixes both:
//  - register hygiene: loop-carried gsrc += WT (no per-iter 64-bit mul),
//    hoisted LDS bases, transient per-bb onorm loads (R4 style) -> ~60 VGPR.
//  - raw barriers: B = asm vmcnt(0)+lgkmcnt(0) + s_barrier (tile nn+1 must
//    land before any wave's k-loop of iter nn+1; B-arrival of all waves
//    guarantees it). C = lgkmcnt(0)-only s_barrier -> the tile-(nn+1) DMA
//    issued at top of iter nn overlaps the whole FMA+logits phase and is
//    never re-drained at C.
//  - XCD pairing: blocks g and g+128 (same XCD, since 128%8==0 and dispatch
//    round-robins blockIdx%8) share each W tile via that XCD's L2.
__global__ __launch_bounds__(1024)
void caps_stage(const float* __restrict__ u, const float* __restrict__ W,
                const float* __restrict__ onorm, float* __restrict__ part)
{
    __shared__ float Wt[2][WT];              // 128 KB double-buffered W tile
    __shared__ float ush[NPB * KK * HB];     // 16 KB: [n][k][b] all 16 n's
    __shared__ float logit_sh[HB * CC];      // 2 KB
    __shared__ float c_sh[HB * CC];          // 2 KB

    const int tid  = threadIdx.x;
    const int wave = tid >> 6;
    const int lane = tid & 63;
    const int bg = tid >> 8;          // 0..3 -> 4 local b's each
    const int cq = tid & 255;         // col-quad 0..255
    const int i0 = cq >> 3;           // capsule 0..31
    const int jq = cq & 7;            // d-quad
    const int b0 = bg << 2;           // local b base
    const int c0 = cq << 2;           // col base

    // pair the two b-halves of an n-group on the SAME XCD for W L2 reuse
    const int ngrp  = blockIdx.x & 127;
    const int bhalf = blockIdx.x >> 7;
    const int n0    = ngrp * NPB;
    const int bbase = bhalf * HB;     // global b offset

    const int woff = wave << 10;      // wave * 1024 floats (4 KB chunk)
    const int loff = lane << 2;       // lane * 4 floats

    float* const l0 = &Wt[0][woff];   // wave-uniform LDS bases, hoisted
    float* const l1 = &Wt[1][woff];
    const float* gsrc = W + (size_t)n0 * WT + woff + loff;  // loop-carried

    // prologue: W tile n0 -> buf0 (16 waves x 4 x 16B/lane)
#pragma unroll
    for (int j = 0; j < 4; ++j) dma16(gsrc + j * 256, l0 + j * 256);
    gsrc += WT;                       // now points at tile n0+1

    // ALL u for this block (16 KB, transposed [n][k][b])
    for (int idx = tid; idx < NPB * KK * HB; idx += 1024) {
        const int n = idx >> 8, rem = idx & 255, k = rem >> 4, b = rem & 15;
        ush[idx] = u[(size_t)(bbase + b) * (NN * KK) + (size_t)(n0 + n) * KK + k];
    }
    __syncthreads();   // drains prologue DMA + ush writes

    float opart[4][4];
#pragma unroll
    for (int bb = 0; bb < 4; ++bb)
#pragma unroll
        for (int m = 0; m < 4; ++m) opart[bb][m] = 0.f;

    for (int nn = 0; nn < NPB; ++nn) {
        // issue next tile's DMA first; it flies across the whole iteration.
        // WAR-safe: buf[(nn+1)&1] reads (k-loop of iter nn-1) were drained by
        // each wave's lgkmcnt(0) before barrier B(nn-1) < C(nn-1) < here.
        if (nn + 1 < NPB) {
            float* ldst = ((nn + 1) & 1) ? l1 : l0;
#pragma unroll
            for (int j = 0; j < 4; ++j) dma16(gsrc + j * 256, ldst + j * 256);
            gsrc += WT;
        }

        const float* Wcur = (nn & 1) ? Wt[1] : Wt[0];
        const float* un = &ush[nn << 8];

        float accU[4][4];
#pragma unroll
        for (int bb = 0; bb < 4; ++bb)
#pragma unroll
            for (int m = 0; m < 4; ++m) accU[bb][m] = 0.f;

#pragma unroll
        for (int k = 0; k < KK; ++k) {
            const float4 w  = *(const float4*)&Wcur[k * NCOL + c0];
            const float4 ub = *(const float4*)&un[(k << 4) + b0];  // u[b0..b0+3][k]
            accU[0][0] = fmaf(ub.x, w.x, accU[0][0]);
            accU[0][1] = fmaf(ub.x, w.y, accU[0][1]);
            accU[0][2] = fmaf(ub.x, w.z, accU[0][2]);
            accU[0][3] = fmaf(ub.x, w.w, accU[0][3]);
            accU[1][0] = fmaf(ub.y, w.x, accU[1][0]);
            accU[1][1] = fmaf(ub.y, w.y, accU[1][1]);
            accU[1][2] = fmaf(ub.y, w.z, accU[1][2]);
            accU[1][3] = fmaf(ub.y, w.w, accU[1][3]);
            accU[2][0] = fmaf(ub.z, w.x, accU[2][0]);
            accU[2][1] = fmaf(ub.z, w.y, accU[2][1]);
            accU[2][2] = fmaf(ub.z, w.z, accU[2][2]);
            accU[2][3] = fmaf(ub.z, w.w, accU[2][3]);
            accU[3][0] = fmaf(ub.w, w.x, accU[3][0]);
            accU[3][1] = fmaf(ub.w, w.y, accU[3][1]);
            accU[3][2] = fmaf(ub.w, w.z, accU[3][2]);
            accU[3][3] = fmaf(ub.w, w.w, accU[3][3]);
        }

        // ---- logits: dot with onorm, transient per-bb loads (4 regs live) ----
#pragma unroll
        for (int bb = 0; bb < 4; ++bb) {
            const float4 on4 = *(const float4*)(
                onorm + ((size_t)(bbase + b0 + bb) * CC + i0) * DD + (jq << 2));
            float p = accU[bb][0] * on4.x + accU[bb][1] * on4.y
                    + accU[bb][2] * on4.z + accU[bb][3] * on4.w;
            p += __shfl_xor(p, 1);
            p += __shfl_xor(p, 2);
            p += __shfl_xor(p, 4);
            if (jq == 0)
                logit_sh[(b0 + bb) * CC + i0] = p;
        }

        // (B) logits visible. vmcnt(0) also guarantees this wave's chunk of
        // tile nn+1 is in LDS; all waves passing B => tile nn+1 fully
        // resident before any wave's k-loop of iter nn+1.
        asm volatile("s_waitcnt vmcnt(0) lgkmcnt(0)" ::: "memory");
        __builtin_amdgcn_s_barrier();

        // ---- softmax over capsules: 512 threads, (b = tid>>5, cap = tid&31) ----
        if (tid < HB * CC) {
            const int b  = tid >> 5;
            const int ii = tid & 31;
            float l = logit_sh[b * CC + ii];
            float mx = l;
#pragma unroll
            for (int msk = 16; msk >= 1; msk >>= 1)
                mx = fmaxf(mx, __shfl_xor(mx, msk));
            const float e = __expf(l - mx);
            float sm = e;
#pragma unroll
            for (int msk = 16; msk >= 1; msk >>= 1)
                sm += __shfl_xor(sm, msk);
            c_sh[b * CC + ii] = e / sm;
        }

        // (C) c ready — lgkm-only drain; the in-flight DMA is NOT drained here.
        asm volatile("s_waitcnt lgkmcnt(0)" ::: "memory");
        __builtin_amdgcn_s_barrier();

        // ---- opart += c * U ----
#pragma unroll
        for (int bb = 0; bb < 4; ++bb) {
            const float cc = c_sh[(b0 + bb) * CC + i0];
#pragma unroll
            for (int m = 0; m < 4; ++m)
                opart[bb][m] = fmaf(cc, accU[bb][m], opart[bb][m]);
        }
    }

    // flush partials, coalesced float4 stores (this block's 16-b half)
    float* my = part + (size_t)ngrp * OSZ + (size_t)bbase * NCOL;
#pragma unroll
    for (int bb = 0; bb < 4; ++bb) {
        float4 v;
        v.x = opart[bb][0]; v.y = opart[bb][1];
        v.z = opart[bb][2]; v.w = opart[bb][3];
        *(float4*)&my[(b0 + bb) * NCOL + c0] = v;
    }
}

// Level-1 reduce: 128 partial images -> NSLICE slice images (8 each).
__global__ __launch_bounds__(256) void caps_reduce1(
    const float* __restrict__ part, float* __restrict__ ws2)
{
    const int gid   = blockIdx.x * 256 + threadIdx.x;     // 0..131071
    const int slice = gid >> 13;                          // 0..15
    const int q     = gid & 8191;                         // col-quad
    float4 acc = make_float4(0.f, 0.f, 0.f, 0.f);
    const float* p = part + ((size_t)slice * 8) * OSZ + (q << 2);
#pragma unroll
    for (int j = 0; j < 8; ++j) {
        const float4 v = *(const float4*)(p + (size_t)j * OSZ);
        acc.x += v.x; acc.y += v.y; acc.z += v.z; acc.w += v.w;
    }
    *(float4*)(ws2 + ((size_t)slice << 15) + ((size_t)q << 2)) = acc;
}

// Level-2 reduce + row op. mode 0: l2-normalize. mode 1: squash.
__global__ __launch_bounds__(256) void caps_reduce2(
    const float* __restrict__ ws2, float* __restrict__ dst, int mode)
{
    const int q = blockIdx.x * 256 + threadIdx.x;         // 0..8191
    float4 acc = make_float4(0.f, 0.f, 0.f, 0.f);
#pragma unroll
    for (int s = 0; s < NSLICE; ++s) {
        const float4 v = *(const float4*)(ws2 + ((size_t)s << 15) + (q << 2));
        acc.x += v.x; acc.y += v.y; acc.z += v.z; acc.w += v.w;
    }
    float s2 = acc.x * acc.x + acc.y * acc.y + acc.z * acc.z + acc.w * acc.w;
    s2 += __shfl_xor(s2, 1);
    s2 += __shfl_xor(s2, 2);
    s2 += __shfl_xor(s2, 4);
    float scale;
    if (mode == 0) {
        scale = rsqrtf(fmaxf(s2, 1e-12f));
    } else {
        scale = (s2 / (1.f + s2)) / sqrtf(s2 + 1e-7f);
    }
    float4 o;
    o.x = acc.x * scale; o.y = acc.y * scale;
    o.z = acc.z * scale; o.w = acc.w * scale;
    *(float4*)(dst + ((size_t)q << 2)) = o;
}

extern "C" void kernel_launch(void* const* d_in, const int* in_sizes, int n_in,
                              void* d_out, int out_size, void* d_ws, size_t ws_size,
                              hipStream_t stream)
{
    const float* u = (const float*)d_in[0];   // (32, 2048, 16)
    const float* W = (const float*)d_in[1];   // (2048, 16, 1024)
    float* out = (float*)d_out;               // (32, 32, 32)

    // ws layout: part (128*32768 fl = 16 MB) | ws2 (2 MB) | onorm (128 KB)
    float* part  = (float*)d_ws;
    float* ws2   = part + (size_t)NGRP * OSZ;
    float* onorm = ws2 + (size_t)NSLICE * OSZ;

    // onorm = 0 => logits 0 => softmax uniform 1/32 (exactly iteration 0)
    hipMemsetAsync(onorm, 0, (size_t)OSZ * sizeof(float), stream);

    for (int it = 0; it < 3; ++it) {
        caps_stage<<<2 * NGRP, 1024, 0, stream>>>(u, W, onorm, part);
        caps_reduce1<<<512, 256, 0, stream>>>(part, ws2);
        if (it < 2)
            caps_reduce2<<<32, 256, 0, stream>>>(ws2, onorm, 0);  // l2-normalize
        else
            caps_reduce2<<<32, 256, 0, stream>>>(ws2, out, 1);    // squash -> d_out
    }
}

// Round 3
// 558.117 us; speedup vs baseline: 2.4248x; 2.4248x over previous
//
#include <hip/hip_runtime.h>
#include <math.h>
#include <stdint.h>

// Problem constants
#define BB   32     // batch
#define HB   16     // batch per block (b-split: 2 blocks per n-group)
#define NN   2048   // input capsules
#define KK   16     // input dim
#define CC   32     // output capsules
#define DD   32     // capsule dim
#define NCOL 1024   // CC*DD
#define NPB  16     // n per block -> 128 n-groups x 2 b-halves = 256 blocks (1/CU)
#define WT   (KK * NCOL)          // 16384 floats = one 64 KB W tile
#define OSZ  (BB * NCOL)          // 32768 floats = one full o/partial image
#define NGRP (NN / NPB)           // 128 partial images

// async global->LDS. Global addr is per-lane; LDS dest must be the
// WAVE-UNIFORM base — HW writes lane i's 16 B at base + 16*i.
__device__ __forceinline__ void dma16(const float* g, const float* l) {
    __builtin_amdgcn_global_load_lds(
        (const __attribute__((address_space(1))) void*)(uintptr_t)g,
        (__attribute__((address_space(3))) void*)(uintptr_t)l,
        16, 0, 0);
}

// Ladder of lessons:
//  R3/R4: 1024-thr blocks are HARD-PINNED at 64 VGPR (56/64/64 across three
//    rounds; __launch_bounds__(,4) and waves_per_eu don't raise it).
//  R5: single->double buffer under that pin spilled ~70 MB/stage.
//  R6: raw-barrier schedule (prefetch at top; B=vmcnt(0)+lgkm(0);
//    C=lgkm(0)-only) verified the overlap works — hbm_gbps hit 3.45 TB/s —
//    but spills exploded to ~1.3 GB/stage round-trip: the structure needs
//    ~110 live VGPRs and 1024-thr blocks only ever get 64.
//  R7 (this): keep the R6 schedule EXACTLY; change the block shape instead.
//    512 threads x 8 waves, same 148 KB LDS -> still 1 block/CU but now
//    2 waves/SIMD -> VGPR ceiling 256. Per-thread: 8 b x 4 cols,
//    accU[8][4]+opart[8][4]=64 acc floats + ~45 others ~ 110 VGPR, no spill.
//    Softmax now uses all 512 threads (HB*CC==blockDim) branch-free.
__global__ __launch_bounds__(512) __attribute__((amdgpu_waves_per_eu(2)))
void caps_stage(const float* __restrict__ u, const float* __restrict__ W,
                const float* __restrict__ onorm, float* __restrict__ part)
{
    __shared__ float Wt[2][WT];              // 128 KB double-buffered W tile
    __shared__ float ush[NPB * KK * HB];     // 16 KB: [n][k][b] all 16 n's
    __shared__ float logit_sh[HB * CC];      // 2 KB
    __shared__ float c_sh[HB * CC];          // 2 KB

    const int tid  = threadIdx.x;
    const int wave = tid >> 6;        // 0..7
    const int lane = tid & 63;
    const int bg = tid >> 8;          // 0..1 -> 8 local b's each
    const int cq = tid & 255;         // col-quad 0..255
    const int i0 = cq >> 3;           // capsule 0..31
    const int jq = cq & 7;            // d-quad
    const int b0 = bg << 3;           // local b base (0 or 8)
    const int c0 = cq << 2;           // col base

    // pair the two b-halves of an n-group on the SAME XCD for W L2 reuse
    const int ngrp  = blockIdx.x & 127;
    const int bhalf = blockIdx.x >> 7;
    const int n0    = ngrp * NPB;
    const int bbase = bhalf * HB;     // global b offset

    const int woff = wave << 11;      // wave * 2048 floats (8 KB chunk)
    const int loff = lane << 2;       // lane * 4 floats

    float* const l0 = &Wt[0][woff];   // wave-uniform LDS bases, hoisted
    float* const l1 = &Wt[1][woff];
    const float* gsrc = W + (size_t)n0 * WT + woff + loff;  // loop-carried

    // prologue: W tile n0 -> buf0 (8 waves x 8 x 16B/lane)
#pragma unroll
    for (int j = 0; j < 8; ++j) dma16(gsrc + j * 256, l0 + j * 256);
    gsrc += WT;                       // now points at tile n0+1

    // ALL u for this block (16 KB, transposed [n][k][b])
    for (int idx = tid; idx < NPB * KK * HB; idx += 512) {
        const int n = idx >> 8, rem = idx & 255, k = rem >> 4, b = rem & 15;
        ush[idx] = u[(size_t)(bbase + b) * (NN * KK) + (size_t)(n0 + n) * KK + k];
    }
    __syncthreads();   // drains prologue DMA + ush writes

    float opart[8][4];
#pragma unroll
    for (int bb = 0; bb < 8; ++bb)
#pragma unroll
        for (int m = 0; m < 4; ++m) opart[bb][m] = 0.f;

    for (int nn = 0; nn < NPB; ++nn) {
        // issue next tile's DMA first; it flies across the whole iteration.
        // WAR-safe: buf[(nn+1)&1] reads (k-loop of iter nn-1) were drained by
        // every wave's lgkmcnt(0) at barrier B(nn-1) < C(nn-1) < here.
        if (nn + 1 < NPB) {
            float* ldst = ((nn + 1) & 1) ? l1 : l0;
#pragma unroll
            for (int j = 0; j < 8; ++j) dma16(gsrc + j * 256, ldst + j * 256);
            gsrc += WT;
        }

        const float* Wcur = (nn & 1) ? Wt[1] : Wt[0];
        const float* un = &ush[nn << 8];

        float accU[8][4];
#pragma unroll
        for (int bb = 0; bb < 8; ++bb)
#pragma unroll
            for (int m = 0; m < 4; ++m) accU[bb][m] = 0.f;

#pragma unroll
        for (int k = 0; k < KK; ++k) {
            const float4 w  = *(const float4*)&Wcur[k * NCOL + c0];
            const float4 ua = *(const float4*)&un[(k << 4) + b0];      // b0..b0+3
            const float4 ubv = *(const float4*)&un[(k << 4) + b0 + 4]; // b0+4..b0+7
            float us[8];
            us[0] = ua.x;  us[1] = ua.y;  us[2] = ua.z;  us[3] = ua.w;
            us[4] = ubv.x; us[5] = ubv.y; us[6] = ubv.z; us[7] = ubv.w;
#pragma unroll
            for (int bb = 0; bb < 8; ++bb) {
                accU[bb][0] = fmaf(us[bb], w.x, accU[bb][0]);
                accU[bb][1] = fmaf(us[bb], w.y, accU[bb][1]);
                accU[bb][2] = fmaf(us[bb], w.z, accU[bb][2]);
                accU[bb][3] = fmaf(us[bb], w.w, accU[bb][3]);
            }
        }

        // ---- logits: dot with onorm, transient per-bb loads (4 regs live) ----
#pragma unroll
        for (int bb = 0; bb < 8; ++bb) {
            const float4 on4 = *(const float4*)(
                onorm + ((size_t)(bbase + b0 + bb) * CC + i0) * DD + (jq << 2));
            float p = accU[bb][0] * on4.x + accU[bb][1] * on4.y
                    + accU[bb][2] * on4.z + accU[bb][3] * on4.w;
            p += __shfl_xor(p, 1);
            p += __shfl_xor(p, 2);
            p += __shfl_xor(p, 4);
            if (jq == 0)
                logit_sh[(b0 + bb) * CC + i0] = p;
        }

        // (B) logits visible. vmcnt(0) also guarantees this wave's chunk of
        // tile nn+1 is in LDS; all waves passing B => tile nn+1 fully
        // resident before any wave's k-loop of iter nn+1.
        asm volatile("s_waitcnt vmcnt(0) lgkmcnt(0)" ::: "memory");
        __builtin_amdgcn_s_barrier();

        // ---- softmax over capsules: all 512 threads, (b = tid>>5, cap = tid&31) ----
        {
            const int b  = tid >> 5;
            const int ii = tid & 31;
            float l = logit_sh[b * CC + ii];
            float mx = l;
#pragma unroll
            for (int msk = 16; msk >= 1; msk >>= 1)
                mx = fmaxf(mx, __shfl_xor(mx, msk));
            const float e = __expf(l - mx);
            float sm = e;
#pragma unroll
            for (int msk = 16; msk >= 1; msk >>= 1)
                sm += __shfl_xor(sm, msk);
            c_sh[b * CC + ii] = e / sm;
        }

        // (C) c ready — lgkm-only drain; the in-flight DMA is NOT drained here.
        asm volatile("s_waitcnt lgkmcnt(0)" ::: "memory");
        __builtin_amdgcn_s_barrier();

        // ---- opart += c * U ----
#pragma unroll
        for (int bb = 0; bb < 8; ++bb) {
            const float cc = c_sh[(b0 + bb) * CC + i0];
#pragma unroll
            for (int m = 0; m < 4; ++m)
                opart[bb][m] = fmaf(cc, accU[bb][m], opart[bb][m]);
        }
    }

    // flush partials, coalesced float4 stores (this block's 16-b half)
    float* my = part + (size_t)ngrp * OSZ + (size_t)bbase * NCOL;
#pragma unroll
    for (int bb = 0; bb < 8; ++bb) {
        float4 v;
        v.x = opart[bb][0]; v.y = opart[bb][1];
        v.z = opart[bb][2]; v.w = opart[bb][3];
        *(float4*)&my[(b0 + bb) * NCOL + c0] = v;
    }
}

// Single-level reduce + row op: 128 partial images -> o, then normalize.
// 8192 threads; each sums 128 independent strided float4s (16 MB total,
// fully memory-level-parallel), then 8-lane shfl for the row norm.
// mode 0: l2-normalize -> onorm. mode 1: squash -> out.
__global__ __launch_bounds__(256) void caps_reduceN(
    const float* __restrict__ part, float* __restrict__ dst, int mode)
{
    const int q = blockIdx.x * 256 + threadIdx.x;         // 0..8191 col-quads
    float4 acc = make_float4(0.f, 0.f, 0.f, 0.f);
    const float* p = part + ((size_t)q << 2);
#pragma unroll 8
    for (int j = 0; j < NGRP; ++j) {
        const float4 v = *(const float4*)(p + (size_t)j * OSZ);
        acc.x += v.x; acc.y += v.y; acc.z += v.z; acc.w += v.w;
    }
    float s2 = acc.x * acc.x + acc.y * acc.y + acc.z * acc.z + acc.w * acc.w;
    s2 += __shfl_xor(s2, 1);
    s2 += __shfl_xor(s2, 2);
    s2 += __shfl_xor(s2, 4);
    float scale;
    if (mode == 0) {
        scale = rsqrtf(fmaxf(s2, 1e-12f));
    } else {
        scale = (s2 / (1.f + s2)) / sqrtf(s2 + 1e-7f);
    }
    float4 o;
    o.x = acc.x * scale; o.y = acc.y * scale;
    o.z = acc.z * scale; o.w = acc.w * scale;
    *(float4*)(dst + ((size_t)q << 2)) = o;
}

extern "C" void kernel_launch(void* const* d_in, const int* in_sizes, int n_in,
                              void* d_out, int out_size, void* d_ws, size_t ws_size,
                              hipStream_t stream)
{
    const float* u = (const float*)d_in[0];   // (32, 2048, 16)
    const float* W = (const float*)d_in[1];   // (2048, 16, 1024)
    float* out = (float*)d_out;               // (32, 32, 32)

    // ws layout: part (128*32768 fl = 16 MB) | onorm (128 KB)
    float* part  = (float*)d_ws;
    float* onorm = part + (size_t)NGRP * OSZ;

    // onorm = 0 => logits 0 => softmax uniform 1/32 (exactly iteration 0)
    hipMemsetAsync(onorm, 0, (size_t)OSZ * sizeof(float), stream);

    for (int it = 0; it < 3; ++it) {
        caps_stage<<<2 * NGRP, 512, 0, stream>>>(u, W, onorm, part);
        if (it < 2)
            caps_reduceN<<<32, 256, 0, stream>>>(part, onorm, 0);  // l2-normalize
        else
            caps_reduceN<<<32, 256, 0, stream>>>(part, out, 1);    // squash -> d_out
    }
}